// Round 9
// baseline (233.510 us; speedup 1.0000x reference)
//
#include <hip/hip_runtime.h>

#define SQL  1024
#define EDIM 256
#define NHD  8
#define NKV  (NHD * 3 * EDIM)   // 6144
#define MROWS (4 * SQL)         // 4096

typedef short bf16x8 __attribute__((ext_vector_type(8)));
typedef float f32x4 __attribute__((ext_vector_type(4)));

__device__ __forceinline__ unsigned short f2bf(float f) {
  unsigned u = __float_as_uint(f);
  u += 0x7fff + ((u >> 16) & 1);   // round-to-nearest-even (finite values)
  return (unsigned short)(u >> 16);
}
__device__ __forceinline__ float bf2f(unsigned short s) {
  return __uint_as_float(((unsigned)s) << 16);
}

// async 16B global->LDS (LDS dest = wave-uniform base + lane*16)
__device__ __forceinline__ void g2lds16(const void* g, void* l) {
  __builtin_amdgcn_global_load_lds(
      (const __attribute__((address_space(1))) unsigned int*)g,
      (__attribute__((address_space(3))) unsigned int*)l, 16, 0, 0);
}

__device__ __forceinline__ void storev(float* p, float v) { *p = v; }
__device__ __forceinline__ void storev(unsigned short* p, float v) { *p = f2bf(v); }

// =====================================================================
// Fused fp32 -> bf16 casts for x, w_attn, w_out (one launch).
// =====================================================================
__global__ __launch_bounds__(256) void cast3_bf16(
    const float* __restrict__ x, unsigned short* __restrict__ xb,
    const float* __restrict__ wa, unsigned short* __restrict__ wb,
    const float* __restrict__ wo, unsigned short* __restrict__ wob) {
  const float* src; unsigned short* dst; int i;
  int blk = blockIdx.x;
  if (blk < 512)       { src = x;  dst = xb;  i = blk * 256 + threadIdx.x; }
  else if (blk < 1280) { src = wa; dst = wb;  i = (blk - 512) * 256 + threadIdx.x; }
  else                 { src = wo; dst = wob; i = (blk - 1280) * 256 + threadIdx.x; }
  float4 a = ((const float4*)src)[2 * i];
  float4 b = ((const float4*)src)[2 * i + 1];
  union { unsigned short s[8]; ulonglong2 v; } u;
  u.s[0] = f2bf(a.x); u.s[1] = f2bf(a.y); u.s[2] = f2bf(a.z); u.s[3] = f2bf(a.w);
  u.s[4] = f2bf(b.x); u.s[5] = f2bf(b.y); u.s[6] = f2bf(b.z); u.s[7] = f2bf(b.w);
  ((ulonglong2*)dst)[i] = u.v;
}

// =====================================================================
// bf16 MFMA NT-GEMM, double-buffered global_load_lds staging.
// =====================================================================
template <int BM, int BN, typename OutT>
__global__ __launch_bounds__(256) void gemm_mfma(
    const unsigned short* __restrict__ A, const unsigned short* __restrict__ B,
    const float* __restrict__ bias, OutT* __restrict__ C,
    int M, int N, int K) {
  constexpr int TM = BM / 32, TN = BN / 32;
  __shared__ __align__(16) unsigned short As[2][BM * 32];
  __shared__ __align__(16) unsigned short Bs[2][BN * 32];
  const int tid = threadIdx.x;
  const int wave = tid >> 6, lane = tid & 63;
  const int quad = lane >> 4, l16 = lane & 15;
  const int wm = (wave >> 1) * (BM / 2), wn = (wave & 1) * (BN / 2);
  const int m0 = blockIdx.x * BM, n0 = blockIdx.y * BN;
  const int sw = (l16 >> 1) & 3;

  f32x4 acc[TM][TN];
  #pragma unroll
  for (int i = 0; i < TM; i++)
    #pragma unroll
    for (int j = 0; j < TN; j++) acc[i][j] = {0.f, 0.f, 0.f, 0.f};

  auto stage = [&](int k0, int bb) {
    #pragma unroll
    for (int it = 0; it < BM / 64; it++) {
      int flat = it * 256 + tid;
      int row = flat >> 2;
      int cg = (flat & 3) ^ ((row >> 1) & 3);
      g2lds16(A + (size_t)(m0 + row) * K + k0 + cg * 8, &As[bb][flat * 8]);
    }
    #pragma unroll
    for (int it = 0; it < BN / 64; it++) {
      int flat = it * 256 + tid;
      int row = flat >> 2;
      int cg = (flat & 3) ^ ((row >> 1) & 3);
      g2lds16(B + (size_t)(n0 + row) * K + k0 + cg * 8, &Bs[bb][flat * 8]);
    }
  };

  stage(0, 0);
  __syncthreads();
  for (int k0 = 0; k0 < K; k0 += 32) {
    const int bb = (k0 >> 5) & 1;
    if (k0 + 32 < K) stage(k0 + 32, bb ^ 1);
    bf16x8 af[TM], bf[TN];
    #pragma unroll
    for (int i = 0; i < TM; i++)
      af[i] = *(const bf16x8*)&As[bb][(wm + i * 16 + l16) * 32 + (quad ^ sw) * 8];
    #pragma unroll
    for (int j = 0; j < TN; j++)
      bf[j] = *(const bf16x8*)&Bs[bb][(wn + j * 16 + l16) * 32 + (quad ^ sw) * 8];
    #pragma unroll
    for (int i = 0; i < TM; i++)
      #pragma unroll
      for (int j = 0; j < TN; j++)
        acc[i][j] = __builtin_amdgcn_mfma_f32_16x16x32_bf16(af[i], bf[j], acc[i][j], 0, 0, 0);
    __syncthreads();
  }

  #pragma unroll
  for (int i = 0; i < TM; i++) {
    #pragma unroll
    for (int r = 0; r < 4; r++) {
      int m = m0 + wm + i * 16 + quad * 4 + r;
      #pragma unroll
      for (int j = 0; j < TN; j++) {
        int n = n0 + wn + j * 16 + l16;
        storev(&C[(size_t)m * N + n], acc[i][j][r] + bias[n]);
      }
    }
  }
}

// =====================================================================
// One-shot V transpose: raw-view V -> Vt[bh][d][s] bf16.
// =====================================================================
__global__ __launch_bounds__(256) void transpose_v(
    const unsigned short* __restrict__ proj, unsigned short* __restrict__ vt) {
  __shared__ unsigned short T[64][66];
  const int tid = threadIdx.x;
  const int s0 = blockIdx.x * 64, d0 = blockIdx.y * 64, bh = blockIdx.z;
  const int b = bh >> 3, h = bh & 7;
  #pragma unroll
  for (int it = 0; it < 2; it++) {
    int c = it * 256 + tid;
    int sr = c >> 3, k8 = (c & 7) * 8;
    int s = s0 + sr;
    const unsigned short* src = proj + (size_t)(b * SQL + h * 128 + (s >> 3)) * NKV
                                + 2 * 2048 + (s & 7) * 256 + d0 + k8;
    *(ulonglong2*)&T[sr][k8] = *(const ulonglong2*)src;
  }
  __syncthreads();
  #pragma unroll
  for (int it = 0; it < 2; it++) {
    int c = it * 256 + tid;
    int dr = c >> 3, s8 = (c & 7) * 8;
    unsigned short tmp[8];
    #pragma unroll
    for (int j = 0; j < 8; j++) tmp[j] = T[s8 + j][dr];
    unsigned short* dst = vt + ((size_t)bh * EDIM + d0 + dr) * SQL + s0 + s8;
    *(ulonglong2*)dst = *(ulonglong2*)tmp;
  }
}

// =====================================================================
// bf16 MFMA flash attention, round 9: occupancy doubling.
// Same uniform split as round 8 (grid 512; pair q-tile 7-j with j ->
// 36 TK=32 tiles; 4 subs of 9 iters; straddling sub = 2 segments).
// Blocks are now 512 threads = 8 waves x 16 q-rows (TQ=128): per-wave
// state halves (o[16]=64 VGPR, aq[8]=32) -> target <=128 VGPR via
// __launch_bounds__(512,4) => 4 waves/SIMD, 16 waves/CU (was 2/8).
// LDS identical: K dbuf 32K | Vt dbuf 32K | Ps 8x(16x40) = 74 KB,
// 2 blocks/CU. Inner-loop swizzles identical to round 8 (verified).
// =====================================================================
__global__ __launch_bounds__(512, 4) void attn_mfma(
    const unsigned short* __restrict__ proj,
    const unsigned short* __restrict__ vt,
    unsigned short* __restrict__ opart,   // [640][128][256] bf16
    float* __restrict__ lpart) {          // [640][128] fp32
  // shorts: K0 @0 | K1 @8192 | V0 @16384 | V1 @24576 | Ps @32768 (8*16*40)
  __shared__ __align__(16) unsigned short lds[37888];

  const int tid = threadIdx.x;
  const int wave = tid >> 6, lane = tid & 63;
  const int quad = lane >> 4, l16 = lane & 15;
  unsigned short* Ps = lds + 32768 + wave * 640;  // [16][40] per wave

  const int g = blockIdx.x;
  const int bh = g & 31;
  const int rem = g >> 5;
  const int j = rem & 3;          // pair id
  const int sb = rem >> 2;        // sub id 0..3
  const int b = bh >> 3, h = bh & 7;
  const int t0 = 4 * (8 - j);     // member0 tile count (32,28,24,20)
  const int m0cnt = (j < 2) ? 4 : 3;   // ceil(t0/9)
  const int s1st  = (j < 2) ? 3 : 2;   // floor(t0/9)
  const int lo = 9 * sb, hi = lo + 9;

  // build up to 2 segments: {qt, local kt start, len, partial slot r}
  int segqt[2], segk0[2], seglen[2], segr[2];
  int nseg = 0;
  if (lo < t0) {  // member0 = q-tile 7-j
    int e = (hi < t0) ? hi : t0;
    segqt[nseg] = 7 - j; segk0[nseg] = lo; seglen[nseg] = e - lo;
    segr[nseg] = sb; nseg++;
  }
  if (hi > t0) {  // member1 = q-tile j
    int a = (lo > t0) ? lo : t0;
    segqt[nseg] = j; segk0[nseg] = a - t0; seglen[nseg] = hi - a;
    segr[nseg] = m0cnt + (sb - s1st); nseg++;
  }

  auto stage = [&](int kt, int bb) {
    unsigned short* KsB = lds + bb * 8192;
    unsigned short* VtB = lds + 16384 + bb * 8192;
    #pragma unroll
    for (int it = 0; it < 2; it++) {   // K tile 32 x 256 (1024 chunks)
      int flat = it * 512 + tid;
      int row = flat >> 5, ch = (flat & 31) ^ (row & 7);
      int s = kt * 32 + row;
      g2lds16(proj + (size_t)(b * SQL + h * 128 + (s >> 3)) * NKV + 2048
                   + (s & 7) * 256 + ch * 8,
              KsB + flat * 8);
    }
    #pragma unroll
    for (int it = 0; it < 2; it++) {   // Vt tile 256 x 32 (1024 chunks)
      int flat = it * 512 + tid;
      int d = flat >> 2, ch = (flat & 3) ^ ((d >> 1) & 3);
      g2lds16(vt + ((size_t)bh * EDIM + d) * SQL + kt * 32 + ch * 8,
              VtB + flat * 8);
    }
  };

  for (int sg = 0; sg < nseg; sg++) {
    const int qt = segqt[sg];
    const int q0 = qt * 128;
    const int c0 = segk0[sg], len = seglen[sg];

    // ---- Q A-frags direct from global (16 rows for this wave) ----
    bf16x8 aq[8];
    {
      int s = q0 + wave * 16 + l16;
      const unsigned short* qrow =
          proj + (size_t)(b * SQL + h * 128 + (s >> 3)) * NKV + (s & 7) * 256;
      #pragma unroll
      for (int kk = 0; kk < 8; kk++)
        aq[kk] = *(const bf16x8*)(qrow + kk * 32 + quad * 8);
    }

    f32x4 o[16];
    #pragma unroll
    for (int tt = 0; tt < 16; tt++) o[tt] = {0.f, 0.f, 0.f, 0.f};
    float l_r[4] = {};

    stage(c0, 0);
    __syncthreads();

    for (int i = 0; i < len; i++) {
      const int kt = c0 + i;
      const int bb = i & 1;
      if (i + 1 < len) stage(kt + 1, bb ^ 1);
      const unsigned short* KsB = lds + bb * 8192;
      const unsigned short* VtB = lds + 16384 + bb * 8192;

      // ---- S = Q K^T : 2 col-tiles ----
      f32x4 s0 = {0.f, 0.f, 0.f, 0.f}, s1 = {0.f, 0.f, 0.f, 0.f};
      #pragma unroll
      for (int kk = 0; kk < 8; kk++) {
        int ch = (kk * 4 + quad) ^ (l16 & 7);
        bf16x8 b0 = *(const bf16x8*)&KsB[l16 * 256 + ch * 8];
        bf16x8 b1 = *(const bf16x8*)&KsB[(16 + l16) * 256 + ch * 8];
        s0 = __builtin_amdgcn_mfma_f32_16x16x32_bf16(aq[kk], b0, s0, 0, 0, 0);
        s1 = __builtin_amdgcn_mfma_f32_16x16x32_bf16(aq[kk], b1, s1, 0, 0, 0);
      }

      // ---- shift-free softmax -> Ps (bf16), lane-local l partials ----
      const int kg0 = kt * 32 + l16, kg1 = kg0 + 16;
      #pragma unroll
      for (int r = 0; r < 4; r++) {
        int qg = q0 + wave * 16 + quad * 4 + r;
        float p0 = (kg0 <= qg) ? __expf(s0[r] * 0.0625f) : 0.f;
        float p1 = (kg1 <= qg) ? __expf(s1[r] * 0.0625f) : 0.f;
        l_r[r] += p0 + p1;
        Ps[(quad * 4 + r) * 40 + l16]      = f2bf(p0);
        Ps[(quad * 4 + r) * 40 + 16 + l16] = f2bf(p1);
      }

      // ---- PV: P C->A via per-wave LDS (no barrier) ----
      bf16x8 ap = *(const bf16x8*)&Ps[l16 * 40 + quad * 8];
      #pragma unroll
      for (int tt = 0; tt < 16; tt++) {
        int ch = quad ^ ((l16 >> 1) & 3);
        bf16x8 bv = *(const bf16x8*)&VtB[(tt * 16 + l16) * 32 + ch * 8];
        o[tt] = __builtin_amdgcn_mfma_f32_16x16x32_bf16(ap, bv, o[tt], 0, 0, 0);
      }
      __syncthreads();  // buffer swap gate + drains prefetch
    }

    // ---- segment epilogue: reduce l, write normalized partial + l ----
    const int slot = (bh * 4 + j) * 5 + segr[sg];
    #pragma unroll
    for (int r = 0; r < 4; r++) {
      float l = l_r[r];
      #pragma unroll
      for (int off = 1; off < 16; off <<= 1) l += __shfl_xor(l, off);
      float inv = (l > 0.f) ? 1.0f / l : 0.f;
      int sl = wave * 16 + quad * 4 + r;   // local q-row [0,128)
      if (l16 == 0) lpart[slot * 128 + sl] = l;
      unsigned short* dst = opart + (size_t)slot * 32768 + sl * 256;
      #pragma unroll
      for (int tt = 0; tt < 16; tt++)
        dst[tt * 16 + l16] = f2bf(o[tt][r] * inv);
    }
  }
}

// =====================================================================
// Merge partials per (bh,qt): obf = sum(O_r * l_r) / sum(l_r),
// written in raw-view layout. Exact (shift-free partials are linear).
// =====================================================================
__global__ __launch_bounds__(256) void combine_split(
    const unsigned short* __restrict__ opart, const float* __restrict__ lpart,
    unsigned short* __restrict__ obf) {
  int idx = blockIdx.x * 256 + threadIdx.x;   // [0, 32*1024*32)
  int row = idx >> 5, oct = idx & 31;
  int bh = row >> 10, s = row & 1023;
  int qt = s >> 7, sl = s & 127;
  int j, r0, rn;
  if (qt >= 4) {        // member0 of pair j = 7-qt
    j = 7 - qt; r0 = 0; rn = (j < 2) ? 4 : 3;
  } else {              // member1 of pair j = qt
    j = qt; int m0 = (j < 2) ? 4 : 3; r0 = m0; rn = 5 - m0;
  }
  int base = (bh * 4 + j) * 5;
  float acc[8] = {};
  float L = 0.f;
  for (int r = r0; r < r0 + rn; r++) {
    int slot = base + r;
    float l = lpart[slot * 128 + sl];
    L += l;
    union { unsigned short s[8]; ulonglong2 v; } u;
    u.v = *(const ulonglong2*)(opart + (size_t)slot * 32768 + sl * 256 + oct * 8);
    #pragma unroll
    for (int k = 0; k < 8; k++) acc[k] += bf2f(u.s[k]) * l;
  }
  float w = 1.0f / L;
  union { unsigned short s[8]; ulonglong2 v; } uo;
  #pragma unroll
  for (int k = 0; k < 8; k++) uo.s[k] = f2bf(acc[k] * w);
  int b = bh >> 3, h = bh & 7;
  unsigned short* dst = obf + (size_t)(b * SQL + h * 128 + (s >> 3)) * 2048
                        + (s & 7) * 256 + oct * 8;
  *(ulonglong2*)dst = uo.v;
}

extern "C" void kernel_launch(void* const* d_in, const int* in_sizes, int n_in,
                              void* d_out, int out_size, void* d_ws, size_t ws_size,
                              hipStream_t stream) {
  const float* x      = (const float*)d_in[0];
  const float* w_attn = (const float*)d_in[1];
  const float* b_attn = (const float*)d_in[2];
  const float* w_out  = (const float*)d_in[3];
  const float* b_out  = (const float*)d_in[4];
  float* out = (float*)d_out;

  // ws: proj 50.3 | vtb 16.8 (reused as obf after attn) | xb 2 | wb 3.1 |
  //     wob 1 | opart 41.9 | lpart 0.33  (~115.7 MB)
  char* p = (char*)d_ws;
  unsigned short* proj  = (unsigned short*)p;  p += (size_t)MROWS * NKV * 2;
  unsigned short* vtb   = (unsigned short*)p;  p += (size_t)32 * EDIM * SQL * 2;
  unsigned short* xb    = (unsigned short*)p;  p += (size_t)MROWS * EDIM * 2;
  unsigned short* wb    = (unsigned short*)p;  p += (size_t)NKV * EDIM * 2;
  unsigned short* wob   = (unsigned short*)p;  p += (size_t)EDIM * 2048 * 2;
  unsigned short* opart = (unsigned short*)p;  p += (size_t)640 * 32768 * 2;
  float*          lpart = (float*)p;
  unsigned short* obf   = vtb;   // vtb is dead after attn_mfma completes

  cast3_bf16<<<1536, 256, 0, stream>>>(x, xb, w_attn, wb, w_out, wob);
  gemm_mfma<128, 128, unsigned short><<<dim3(MROWS / 128, NKV / 128), 256, 0, stream>>>(
      xb, wb, b_attn, proj, MROWS, NKV, EDIM);
  transpose_v<<<dim3(SQL / 64, EDIM / 64, 32), 256, 0, stream>>>(proj, vtb);
  attn_mfma<<<512, 512, 0, stream>>>(proj, vtb, opart, lpart);
  combine_split<<<4096, 256, 0, stream>>>(opart, lpart, obf);
  gemm_mfma<64, 64, float><<<dim3(MROWS / 64, EDIM / 64), 256, 0, stream>>>(
      obf, wob, b_out, out, MROWS, EDIM, NHD * EDIM);
}